// Round 1
// baseline (149.665 us; speedup 1.0000x reference)
//
#include <hip/hip_runtime.h>
#include <math.h>

#define BATCH 64
#define TOBS (1000 * 128)        // observations per batch
#define GROUPS (TOBS / 4)        // 32000 groups of 4 obs (12 floats, 48 B)
#define BPB 25                   // blocks per batch: 25*256*5 == 32000 exactly
#define BLOCK 256

__global__ __launch_bounds__(BLOCK) void score_kernel(const float* __restrict__ z,
                                                      const float* __restrict__ R,
                                                      float* __restrict__ ws,
                                                      float thresh2) {
    const int b = blockIdx.x / BPB;
    const int chunk = blockIdx.x % BPB;
    const float r = R[b];
    const float Bc = -0.5f / (r * r);
    const float4* __restrict__ zb = (const float4*)(z + (size_t)b * (TOBS * 3));

    float acc = 0.0f;
    // exactly 5 iterations per thread; consecutive threads read consecutive 48B groups
    for (int g = chunk * BLOCK + threadIdx.x; g < GROUPS; g += BPB * BLOCK) {
        const float4 a0 = zb[g * 3 + 0];
        const float4 a1 = zb[g * 3 + 1];
        const float4 a2 = zb[g * 3 + 2];
        const float z20 = a0.x * a0.x + a0.y * a0.y + a0.z * a0.z;
        const float z21 = a0.w * a0.w + a1.x * a1.x + a1.y * a1.y;
        const float z22 = a1.z * a1.z + a1.w * a1.w + a2.x * a2.x;
        const float z23 = a2.y * a2.y + a2.z * a2.z + a2.w * a2.w;
        acc += (z20 < thresh2) ? __expf(Bc * z20) : 0.0f;
        acc += (z21 < thresh2) ? __expf(Bc * z21) : 0.0f;
        acc += (z22 < thresh2) ? __expf(Bc * z22) : 0.0f;
        acc += (z23 < thresh2) ? __expf(Bc * z23) : 0.0f;
    }

    // wave-64 butterfly reduce
    #pragma unroll
    for (int off = 32; off > 0; off >>= 1)
        acc += __shfl_down(acc, off, 64);

    __shared__ float wave_sums[BLOCK / 64];
    const int wave = threadIdx.x >> 6;
    const int lane = threadIdx.x & 63;
    if (lane == 0) wave_sums[wave] = acc;
    __syncthreads();
    if (threadIdx.x == 0) {
        float t = 0.0f;
        #pragma unroll
        for (int w = 0; w < BLOCK / 64; ++w) t += wave_sums[w];
        atomicAdd(&ws[b], t);   // device-scope by default on CDNA
    }
}

__global__ void finalize_kernel(const float* __restrict__ ws,
                                const float* __restrict__ R,
                                const float* __restrict__ num_obs,
                                float* __restrict__ out,
                                float thresh2) {
    const int b = threadIdx.x;
    if (b >= BATCH) return;
    const float r = R[b];
    const float A = 1.0f / (r * r);
    const float half = 0.5f * A * thresh2;
    const float mu_p = (1.0f - expf(-half)) / (2.0f * A);
    const float e2 = (1.0f - expf(-2.0f * half)) / (4.0f * A);
    const float var = e2 - mu_p * mu_p;
    const float nobs = num_obs[0];
    const float mu = nobs * mu_p;
    const float s2 = nobs * var;
    const float rs = ws[b];
    out[b] = rs;                       // raw_score
    out[BATCH + b] = mu;               // mu
    out[2 * BATCH + b] = s2;           // sigma2
    out[3 * BATCH + b] = rs - mu - s2; // objective
}

extern "C" void kernel_launch(void* const* d_in, const int* in_sizes, int n_in,
                              void* d_out, int out_size, void* d_ws, size_t ws_size,
                              hipStream_t stream) {
    const float* z = (const float*)d_in[0];        // (64,1000,128,3) f32
    const float* R = (const float*)d_in[1];        // (64,1) f32
    const float* num_obs = (const float*)d_in[2];  // scalar f32
    float* out = (float*)d_out;                    // 4*64 f32, concatenated
    float* ws = (float*)d_ws;                      // 64-float accumulator

    // THRESH2 exactly as numpy computes it (double math, then f32 cast)
    const double th = 2.0 * sin(M_PI / 180.0);     // = 2*sin(deg2rad(2)/2)
    const float thresh2 = (float)(th * th);

    hipMemsetAsync(ws, 0, BATCH * sizeof(float), stream);
    score_kernel<<<dim3(BATCH * BPB), dim3(BLOCK), 0, stream>>>(z, R, ws, thresh2);
    finalize_kernel<<<dim3(1), dim3(64), 0, stream>>>(ws, R, num_obs, out, thresh2);
}

// Round 2
// 144.823 us; speedup vs baseline: 1.0334x; 1.0334x over previous
//
#include <hip/hip_runtime.h>
#include <math.h>

#define BATCH 64
#define TOBS (1000 * 128)        // observations per batch
#define GROUPS (TOBS / 4)        // 32000 groups of 4 obs (12 floats, 48 B)
#define BPB 25                   // blocks per batch: 25*256*5 == 32000 exactly
#define BLOCK 256

// Per-block partial sums -> ws[BATCH*BPB]; no memset / atomics needed.
__global__ __launch_bounds__(BLOCK) void score_kernel(const float* __restrict__ z,
                                                      const float* __restrict__ R,
                                                      float* __restrict__ ws,
                                                      float thresh2) {
    const int b = blockIdx.x / BPB;
    const int chunk = blockIdx.x % BPB;
    const float r = R[b];
    const float Bc = -0.5f / (r * r);
    const float4* __restrict__ zb = (const float4*)(z + (size_t)b * (TOBS * 3));

    float acc = 0.0f;
    const int g0 = chunk * BLOCK + threadIdx.x;
    // exactly 5 iterations, always in range: max g = 24*256+255 + 4*6400 = 31999
    #pragma unroll
    for (int i = 0; i < 5; ++i) {
        const int g = g0 + i * (BPB * BLOCK);
        const float4 a0 = zb[g * 3 + 0];
        const float4 a1 = zb[g * 3 + 1];
        const float4 a2 = zb[g * 3 + 2];
        const float z20 = a0.x * a0.x + a0.y * a0.y + a0.z * a0.z;
        const float z21 = a0.w * a0.w + a1.x * a1.x + a1.y * a1.y;
        const float z22 = a1.z * a1.z + a1.w * a1.w + a2.x * a2.x;
        const float z23 = a2.y * a2.y + a2.z * a2.z + a2.w * a2.w;
        acc += (z20 < thresh2) ? __expf(Bc * z20) : 0.0f;
        acc += (z21 < thresh2) ? __expf(Bc * z21) : 0.0f;
        acc += (z22 < thresh2) ? __expf(Bc * z22) : 0.0f;
        acc += (z23 < thresh2) ? __expf(Bc * z23) : 0.0f;
    }

    // wave-64 butterfly reduce
    #pragma unroll
    for (int off = 32; off > 0; off >>= 1)
        acc += __shfl_down(acc, off, 64);

    __shared__ float wave_sums[BLOCK / 64];
    const int wave = threadIdx.x >> 6;
    const int lane = threadIdx.x & 63;
    if (lane == 0) wave_sums[wave] = acc;
    __syncthreads();
    if (threadIdx.x == 0) {
        float t = 0.0f;
        #pragma unroll
        for (int w = 0; w < BLOCK / 64; ++w) t += wave_sums[w];
        ws[blockIdx.x] = t;    // per-block partial, no atomic
    }
}

__global__ void finalize_kernel(const float* __restrict__ ws,
                                const float* __restrict__ R,
                                const float* __restrict__ num_obs,
                                float* __restrict__ out,
                                float thresh2) {
    const int b = threadIdx.x;
    if (b >= BATCH) return;

    float rs = 0.0f;
    #pragma unroll
    for (int c = 0; c < BPB; ++c) rs += ws[b * BPB + c];

    const float r = R[b];
    const float A = 1.0f / (r * r);
    const float half = 0.5f * A * thresh2;
    const float mu_p = (1.0f - expf(-half)) / (2.0f * A);
    const float e2 = (1.0f - expf(-2.0f * half)) / (4.0f * A);
    const float var = e2 - mu_p * mu_p;
    const float nobs = num_obs[0];
    const float mu = nobs * mu_p;
    const float s2 = nobs * var;
    out[b] = rs;                       // raw_score
    out[BATCH + b] = mu;               // mu
    out[2 * BATCH + b] = s2;           // sigma2
    out[3 * BATCH + b] = rs - mu - s2; // objective
}

extern "C" void kernel_launch(void* const* d_in, const int* in_sizes, int n_in,
                              void* d_out, int out_size, void* d_ws, size_t ws_size,
                              hipStream_t stream) {
    const float* z = (const float*)d_in[0];        // (64,1000,128,3) f32
    const float* R = (const float*)d_in[1];        // (64,1) f32
    const float* num_obs = (const float*)d_in[2];  // scalar f32
    float* out = (float*)d_out;                    // 4*64 f32, concatenated
    float* ws = (float*)d_ws;                      // 1600 partials

    // THRESH2 exactly as numpy computes it (double math, then f32 cast)
    const double th = 2.0 * sin(M_PI / 180.0);     // = 2*sin(deg2rad(2)/2)
    const float thresh2 = (float)(th * th);

    score_kernel<<<dim3(BATCH * BPB), dim3(BLOCK), 0, stream>>>(z, R, ws, thresh2);
    finalize_kernel<<<dim3(1), dim3(64), 0, stream>>>(ws, R, num_obs, out, thresh2);
}